// Round 15
// baseline (81.166 us; speedup 1.0000x reference)
//
#include <hip/hip_runtime.h>
#include <hip/hip_bf16.h>

using f32x4   = __attribute__((ext_vector_type(4))) float;
using short8  = __attribute__((ext_vector_type(8))) short;
using short4v = __attribute__((ext_vector_type(4))) short;

#define LOG2_2PI 2.6514961294723187f   // log2(2*pi)
#define L2E_HALF 0.7213475204444817f   // 0.5*log2(e)
#define HP2 640   // padded phoneme axis (10 x 64-chunks; 1280B encT rows)

__device__ __forceinline__ short bf16bits(float x) {
  unsigned u = __builtin_bit_cast(unsigned, x);
  u = (u + 0x7FFFu + ((u >> 16) & 1u)) >> 16;   // RNE; inputs are finite
  return (short)u;
}
__device__ __forceinline__ float bf16round(float x) {
  unsigned u = __builtin_bit_cast(unsigned, x);
  u = ((u + 0x7FFFu + ((u >> 16) & 1u)) >> 16) << 16;
  return __builtin_bit_cast(float, u);
}

// Kernel 0: packed params pk[b][h] = {c, q2, b2(masked), 0} for h in [0,HP2),
// plus per-batch aux = {Gmax, q2Min, q2Max, b2Min, b2Max} over valid h (< L).
__global__ void prep_kernel(const float* __restrict__ dur,
                            const float* __restrict__ vars,
                            const int* __restrict__ lens,
                            f32x4* __restrict__ pk, float* __restrict__ aux,
                            int H) {
  const int b = blockIdx.x;
  const int l = threadIdx.x;
  const int L = lens[b];
  float run = 0.f, prevD = 0.f;
  float Gmax = 0.f, qMin = 1e30f, qMax = 0.f, bMin = 1e30f, bMax = -1e30f;
  for (int h0 = 0; h0 < HP2; h0 += 64) {
    const int h = h0 + l;
    const float d = (h < H) ? dur[(size_t)b * H + h] : 0.f;
    float x = d;
#pragma unroll
    for (int off = 1; off < 64; off <<= 1) {
      float y = __shfl_up(x, off);
      if (l >= off) x += y;
    }
    float dp = __shfl_up(d, 1);
    if (l == 0) dp = prevD;
    f32x4 e = (f32x4){0.f, 0.f, -1e30f, 0.f};
    if (h < H) {
      const float v = vars[(size_t)b * H + h];
      const float q = L2E_HALF / v;
      const float bc = -0.5f * (LOG2_2PI + __builtin_amdgcn_logf(v));
      e[0] = run + x - 0.5f * d;
      e[1] = q;
      e[2] = (h < L) ? bc : -1e30f;
      if (h < L) {
        qMin = fminf(qMin, q); qMax = fmaxf(qMax, q);
        bMin = fminf(bMin, bc); bMax = fmaxf(bMax, bc);
        if (h >= 1) Gmax = fmaxf(Gmax, 0.5f * (d + dp));  // center gap
      }
    }
    pk[(size_t)b * HP2 + h] = e;
    prevD = __shfl(d, 63);
    run += __shfl(x, 63);
  }
#pragma unroll
  for (int off = 1; off < 64; off <<= 1) {
    qMin = fminf(qMin, __shfl_xor(qMin, off));
    qMax = fmaxf(qMax, __shfl_xor(qMax, off));
    bMin = fminf(bMin, __shfl_xor(bMin, off));
    bMax = fmaxf(bMax, __shfl_xor(bMax, off));
    Gmax = fmaxf(Gmax, __shfl_xor(Gmax, off));
  }
  if (l == 0) {
    float* ax = aux + b * 8;
    ax[0] = Gmax; ax[1] = qMin; ax[2] = qMax; ax[3] = bMin; ax[4] = bMax;
  }
}

// Kernel 1 (R7/R8 verified): per (b, 32-frame tile) conservative chunk window
// via binary search over monotone centers. win[(b*TT+tile)] = {cLo, cHi}.
__global__ void win_kernel(const f32x4* __restrict__ pk,
                           const float* __restrict__ aux,
                           const int* __restrict__ lens,
                           int* __restrict__ win, int T, int TT) {
  const int b = blockIdx.x;
  const int L = lens[b];
  const float Gmax = aux[b * 8 + 0], qMn = aux[b * 8 + 1], qMx = aux[b * 8 + 2];
  const float bMn  = aux[b * 8 + 3], bMx = aux[b * 8 + 4];
  const f32x4* pc = pk + (size_t)b * HP2;
  const float c0 = pc[0][0], cL = pc[L - 1][0];
  for (int tile = threadIdx.x; tile < TT; tile += blockDim.x) {
    const float tLo = (float)(tile * 32);
    const float tHi = (float)(min(tile * 32 + 31, T - 1));
    const float D0 = fmaxf(0.5f * Gmax, fmaxf(fmaxf(c0 - tLo, tHi - cL), 0.f));
    const float Wr = __fsqrt_rn(((bMx - bMn) + 65.f + qMx * D0 * D0) / qMn);
    int lo = 0, hi = L;
    const float thLo = tLo - Wr;
    while (lo < hi) { const int mid = (lo + hi) >> 1; if (pc[mid][0] < thLo) lo = mid + 1; else hi = mid; }
    int hLo = lo;
    int lo2 = hLo, hi2 = L;
    const float thHi = tHi + Wr;
    while (lo2 < hi2) { const int mid = (lo2 + hi2) >> 1; if (pc[mid][0] <= thHi) lo2 = mid + 1; else hi2 = mid; }
    int hHi = lo2;
    if (hHi <= hLo) { hLo = max(hLo - 1, 0); hHi = min(hLo + 2, L); }
    win[(b * TT + tile) * 2 + 0] = hLo >> 6;
    win[(b * TT + tile) * 2 + 1] = (hHi + 63) >> 6;
  }
}

// Kernel 2: enc [B][H][D] f32 -> encT [B][D][HP2] bf16. Chunks wholly beyond
// ceil(L/64)*64 are never read by gup -> skip those blocks (verified R13).
__global__ void transpose_kernel(const float* __restrict__ enc,
                                 short* __restrict__ encT,
                                 const int* __restrict__ lens,
                                 int H, int D) {
  __shared__ short sT[64][66];
  const int b  = blockIdx.z;
  const int h0 = blockIdx.y * 64;
  const int d0 = blockIdx.x * 64;
  const int Lpad = (lens[b] + 63) & ~63;
  if (h0 >= Lpad) return;
  const int tid = threadIdx.x;

  const int dc = (tid & 15) * 4;
  const int hr = tid >> 4;
#pragma unroll
  for (int ps = 0; ps < 4; ++ps) {
    const int hh = hr + ps * 16;
    const int h  = h0 + hh;
    f32x4 v = (h < H) ? *(const f32x4*)&enc[((size_t)b * H + h) * D + d0 + dc]
                      : (f32x4){0.f, 0.f, 0.f, 0.f};
#pragma unroll
    for (int j = 0; j < 4; ++j) sT[dc + j][hh] = bf16bits(v[j]);
  }
  __syncthreads();

  const int tx4 = (tid & 15) * 4;
  const int ty2 = tid >> 4;
#pragma unroll
  for (int i = 0; i < 4; ++i) {
    const int d = d0 + ty2 + i * 16;
    short4v v;
#pragma unroll
    for (int j = 0; j < 4; ++j) v[j] = sT[ty2 + i * 16][tx4 + j];
    *(short4v*)&encT[((size_t)b * D + d) * HP2 + h0 + tx4] = v;
  }
}

// Main fused kernel (merged d-halves): block = (32-frame tile, batch),
// 512 threads = 8 waves; wave w owns d in [64w, 64w+64). Per-tile staging,
// premax, A-build, and chunk-skip now run ONCE per tile (R14 ran them twice,
// once per d-half). Per-thread accumulator footprint unchanged (acc[2][4]).
__launch_bounds__(512, 4)
__global__ void gup_kernel(const short* __restrict__ encT,
                           const f32x4* __restrict__ pk,
                           const int* __restrict__ win,
                           float* __restrict__ out,
                           int T, int TT) {
  constexpr int D  = 512;
  constexpr int AS = 72;           // sA row stride in halves (144B, 16B-aligned)

  __shared__ __align__(16) float sc[HP2], sq[HP2], sb[HP2];
  __shared__ float sden[32];
  __shared__ short sA[2][32 * AS];

  const int tid  = threadIdx.x;
  const int b    = blockIdx.y;
  const int tIdx = blockIdx.x;
  const int t0   = tIdx * 32;

  const int cLo = win[(b * TT + tIdx) * 2 + 0];
  const int cHi = win[(b * TT + tIdx) * 2 + 1];
  const int base = cLo * 64;
  const int nC   = cHi - cLo;
  const int W64  = nC * 64;

  // phase 0: windowed packed params -> LDS (relative indexing)
  for (int i = tid; i < W64; i += 512) {
    const f32x4 v = pk[(size_t)b * HP2 + base + i];
    sc[i] = v[0]; sq[i] = v[1]; sb[i] = v[2];
  }
  __syncthreads();

  // premax: exact per-frame max over the window (16 lanes/frame, float4 reads)
  const int tfA  = tid >> 4;              // frame 0..31
  const int hs16 = tid & 15;
  const int k4   = hs16 * 4;              // this thread's 4 k-slots in sA
  const float tA = (float)(t0 + tfA);
  float mA = -1e30f;
  for (int h4 = k4; h4 < W64; h4 += 64) {
    const f32x4 cv = *(const f32x4*)&sc[h4];
    const f32x4 qv = *(const f32x4*)&sq[h4];
    const f32x4 bv = *(const f32x4*)&sb[h4];
#pragma unroll
    for (int j = 0; j < 4; ++j) {
      const float dd = tA - cv[j];
      mA = fmaxf(mA, fmaf(-dd * dd, qv[j], bv[j]));
    }
  }
  mA = fmaxf(mA, __shfl_xor(mA, 1));
  mA = fmaxf(mA, __shfl_xor(mA, 2));
  mA = fmaxf(mA, __shfl_xor(mA, 4));
  mA = fmaxf(mA, __shfl_xor(mA, 8));

  const int lane = tid & 63;
  const int wv   = tid >> 6;              // wave 0..7 -> d base 64*wv
  const int l15  = lane & 15;
  const int lq   = lane >> 4;

  f32x4 acc[2][4];
#pragma unroll
  for (int i = 0; i < 2; ++i)
#pragma unroll
    for (int j = 0; j < 4; ++j) acc[i][j] = (f32x4){0.f, 0.f, 0.f, 0.f};

  float denAcc = 0.f;
  const short* bp = encT + ((size_t)b * D + wv * 64 + l15) * HP2 + base + lq * 8;

  int p = 0;
  for (int cc = 0; cc < nC; ++cc) {
    // A tile: unnormalized weights w = exp2(score - m), bf16 (RNE)
    const int hb = cc * 64 + k4;
    const f32x4 cv0 = *(const f32x4*)&sc[hb];
    const f32x4 qv0 = *(const f32x4*)&sq[hb];
    const f32x4 bv0 = *(const f32x4*)&sb[hb];
    short4v w;
    float denAdd = 0.f, pmax = 0.f;
#pragma unroll
    for (int j = 0; j < 4; ++j) {
      const float dd = tA - cv0[j];
      const float pv = __builtin_amdgcn_exp2f(fmaf(-dd * dd, qv0[j], bv0[j]) - mA);
      w[j] = bf16bits(pv);
      denAdd += bf16round(pv);
      pmax = fmaxf(pmax, pv);
    }

    // exact chunk skip: all weights < 2^-66 relative -> contributes nothing
    if (!__syncthreads_or(pmax > 1e-20f)) continue;

    denAcc += denAdd;
    *(short4v*)&sA[p][tfA * AS + k4] = w;
    __syncthreads();

    // two 32-k sub-steps
#pragma unroll
    for (int kh = 0; kh < 2; ++kh) {
      short8 bfv[4];
#pragma unroll
      for (int nt = 0; nt < 4; ++nt)
        bfv[nt] = *(const short8*)(bp + (size_t)nt * 16 * HP2 + cc * 64 + kh * 32);
      short8 af[2];
#pragma unroll
      for (int mt = 0; mt < 2; ++mt)
        af[mt] = *(short8*)&sA[p][(mt * 16 + l15) * AS + kh * 32 + lq * 8];
      // swapped operands: acc holds C[d][t] -> lane gets 4 consecutive d
#pragma unroll
      for (int mt = 0; mt < 2; ++mt)
#pragma unroll
        for (int nt = 0; nt < 4; ++nt)
          acc[mt][nt] = __builtin_amdgcn_mfma_f32_16x16x32_bf16(bfv[nt], af[mt], acc[mt][nt], 0, 0, 0);
    }
    p ^= 1;   // double-buffered sA; or-barrier + barrier separate reuse
  }

  // denominators: reduce the 16 threads sharing a frame
  {
    float dsum = denAcc;
    dsum += __shfl_xor(dsum, 1);
    dsum += __shfl_xor(dsum, 2);
    dsum += __shfl_xor(dsum, 4);
    dsum += __shfl_xor(dsum, 8);
    if (hs16 == 0) sden[tfA] = dsum;
  }
  __syncthreads();

  // epilogue: normalize and store float4 (4 consecutive d per thread)
#pragma unroll
  for (int mt = 0; mt < 2; ++mt) {
    const int tg = t0 + mt * 16 + l15;
    const float inv = 1.0f / sden[mt * 16 + l15];
    if (tg < T) {
#pragma unroll
      for (int nt = 0; nt < 4; ++nt) {
        f32x4 o;
#pragma unroll
        for (int i = 0; i < 4; ++i) o[i] = acc[mt][nt][i] * inv;
        *(f32x4*)&out[((size_t)b * T + tg) * D + wv * 64 + nt * 16 + lq * 4] = o;
      }
    }
  }
}

extern "C" void kernel_launch(void* const* d_in, const int* in_sizes, int n_in,
                              void* d_out, int out_size, void* d_ws, size_t ws_size,
                              hipStream_t stream) {
  const float* enc  = (const float*)d_in[0];
  const float* dur  = (const float*)d_in[1];
  const float* vars = (const float*)d_in[2];
  const int*   lens = (const int*)d_in[3];

  const int B = in_sizes[3];
  const int H = in_sizes[1] / B;
  const int D = in_sizes[0] / in_sizes[1];
  const int T = out_size / (B * D);
  const int TT = (T + 31) / 32;
  (void)n_in; (void)ws_size;

  f32x4* pk  = (f32x4*)d_ws;                       // B*HP2 float4
  float* aux = (float*)(pk + (size_t)B * HP2);     // B*8
  int*   wn  = (int*)(aux + 8 * (size_t)B);        // B*TT*2
  short* encT = (short*)(wn + (size_t)B * TT * 2); // B*D*HP2 bf16 ~= 21 MB

  prep_kernel<<<B, 64, 0, stream>>>(dur, vars, lens, pk, aux, H);

  win_kernel<<<B, 128, 0, stream>>>(pk, aux, lens, wn, T, TT);

  dim3 tgrid(D / 64, HP2 / 64, B);
  transpose_kernel<<<tgrid, 256, 0, stream>>>(enc, encT, lens, H, D);

  dim3 grid(TT, B);
  gup_kernel<<<grid, 512, 0, stream>>>(encT, pk, wn, (float*)d_out, T, TT);
}

// Round 16
// 72.204 us; speedup vs baseline: 1.1241x; 1.1241x over previous
//
#include <hip/hip_runtime.h>
#include <hip/hip_bf16.h>

using f32x4   = __attribute__((ext_vector_type(4))) float;
using short8  = __attribute__((ext_vector_type(8))) short;
using short4v = __attribute__((ext_vector_type(4))) short;

#define LOG2_2PI 2.6514961294723187f   // log2(2*pi)
#define L2E_HALF 0.7213475204444817f   // 0.5*log2(e)
#define HP2 640   // padded phoneme axis (10 x 64-chunks; 1280B encT rows)

__device__ __forceinline__ short bf16bits(float x) {
  unsigned u = __builtin_bit_cast(unsigned, x);
  u = (u + 0x7FFFu + ((u >> 16) & 1u)) >> 16;   // RNE; inputs are finite
  return (short)u;
}
__device__ __forceinline__ float bf16round(float x) {
  unsigned u = __builtin_bit_cast(unsigned, x);
  u = ((u + 0x7FFFu + ((u >> 16) & 1u)) >> 16) << 16;
  return __builtin_bit_cast(float, u);
}

// Kernel 0 (fused prep+win): one block per batch, 128 threads (2 waves).
// Wave 0: duration prefix-scan -> packed params pk[b][h] = {c, q2, b2, 0}
// (b2 = -1e30 for h >= L), centers + aux mirrored to LDS.
// Then ALL threads: per-32-frame-tile conservative chunk windows via binary
// search over LDS centers (R7/R8-verified radius bound).
__global__ void prepwin_kernel(const float* __restrict__ dur,
                               const float* __restrict__ vars,
                               const int* __restrict__ lens,
                               f32x4* __restrict__ pk, int* __restrict__ win,
                               int H, int T, int TT) {
  __shared__ float sc[HP2];
  __shared__ float sAux[8];

  const int b   = blockIdx.x;
  const int tid = threadIdx.x;
  const int L   = lens[b];

  if (tid < 64) {
    const int l = tid;
    float run = 0.f, prevD = 0.f;
    float Gmax = 0.f, qMin = 1e30f, qMax = 0.f, bMin = 1e30f, bMax = -1e30f;
    for (int h0 = 0; h0 < HP2; h0 += 64) {
      const int h = h0 + l;
      const float d = (h < H) ? dur[(size_t)b * H + h] : 0.f;
      float x = d;
#pragma unroll
      for (int off = 1; off < 64; off <<= 1) {
        float y = __shfl_up(x, off);
        if (l >= off) x += y;
      }
      float dp = __shfl_up(d, 1);
      if (l == 0) dp = prevD;
      f32x4 e = (f32x4){0.f, 0.f, -1e30f, 0.f};
      if (h < H) {
        const float v = vars[(size_t)b * H + h];
        const float q = L2E_HALF / v;
        const float bc = -0.5f * (LOG2_2PI + __builtin_amdgcn_logf(v));
        e[0] = run + x - 0.5f * d;
        e[1] = q;
        e[2] = (h < L) ? bc : -1e30f;
        if (h < L) {
          qMin = fminf(qMin, q); qMax = fmaxf(qMax, q);
          bMin = fminf(bMin, bc); bMax = fmaxf(bMax, bc);
          if (h >= 1) Gmax = fmaxf(Gmax, 0.5f * (d + dp));  // center gap
        }
      }
      pk[(size_t)b * HP2 + h] = e;
      sc[h] = e[0];
      prevD = __shfl(d, 63);
      run += __shfl(x, 63);
    }
#pragma unroll
    for (int off = 1; off < 64; off <<= 1) {
      qMin = fminf(qMin, __shfl_xor(qMin, off));
      qMax = fmaxf(qMax, __shfl_xor(qMax, off));
      bMin = fminf(bMin, __shfl_xor(bMin, off));
      bMax = fmaxf(bMax, __shfl_xor(bMax, off));
      Gmax = fmaxf(Gmax, __shfl_xor(Gmax, off));
    }
    if (l == 0) {
      sAux[0] = Gmax; sAux[1] = qMin; sAux[2] = qMax; sAux[3] = bMin; sAux[4] = bMax;
    }
  }
  __syncthreads();

  const float Gmax = sAux[0], qMn = sAux[1], qMx = sAux[2];
  const float bMn  = sAux[3], bMx = sAux[4];
  const float c0 = sc[0], cL = sc[L - 1];
  for (int tile = tid; tile < TT; tile += 128) {
    const float tLo = (float)(tile * 32);
    const float tHi = (float)(min(tile * 32 + 31, T - 1));
    const float D0 = fmaxf(0.5f * Gmax, fmaxf(fmaxf(c0 - tLo, tHi - cL), 0.f));
    const float Wr = __fsqrt_rn(((bMx - bMn) + 65.f + qMx * D0 * D0) / qMn);
    int lo = 0, hi = L;
    const float thLo = tLo - Wr;
    while (lo < hi) { const int mid = (lo + hi) >> 1; if (sc[mid] < thLo) lo = mid + 1; else hi = mid; }
    int hLo = lo;
    int lo2 = hLo, hi2 = L;
    const float thHi = tHi + Wr;
    while (lo2 < hi2) { const int mid = (lo2 + hi2) >> 1; if (sc[mid] <= thHi) lo2 = mid + 1; else hi2 = mid; }
    int hHi = lo2;
    if (hHi <= hLo) { hLo = max(hLo - 1, 0); hHi = min(hLo + 2, L); }
    win[(b * TT + tile) * 2 + 0] = hLo >> 6;
    win[(b * TT + tile) * 2 + 1] = (hHi + 63) >> 6;
  }
}

// Kernel 1: enc [B][H][D] f32 -> encT [B][D][HP2] bf16. Chunks wholly beyond
// ceil(L/64)*64 are never read by gup -> skip those blocks (verified R13).
__global__ void transpose_kernel(const float* __restrict__ enc,
                                 short* __restrict__ encT,
                                 const int* __restrict__ lens,
                                 int H, int D) {
  __shared__ short sT[64][66];
  const int b  = blockIdx.z;
  const int h0 = blockIdx.y * 64;
  const int d0 = blockIdx.x * 64;
  const int Lpad = (lens[b] + 63) & ~63;
  if (h0 >= Lpad) return;
  const int tid = threadIdx.x;

  const int dc = (tid & 15) * 4;
  const int hr = tid >> 4;
#pragma unroll
  for (int ps = 0; ps < 4; ++ps) {
    const int hh = hr + ps * 16;
    const int h  = h0 + hh;
    f32x4 v = (h < H) ? *(const f32x4*)&enc[((size_t)b * H + h) * D + d0 + dc]
                      : (f32x4){0.f, 0.f, 0.f, 0.f};
#pragma unroll
    for (int j = 0; j < 4; ++j) sT[dc + j][hh] = bf16bits(v[j]);
  }
  __syncthreads();

  const int tx4 = (tid & 15) * 4;
  const int ty2 = tid >> 4;
#pragma unroll
  for (int i = 0; i < 4; ++i) {
    const int d = d0 + ty2 + i * 16;
    short4v v;
#pragma unroll
    for (int j = 0; j < 4; ++j) v[j] = sT[ty2 + i * 16][tx4 + j];
    *(short4v*)&encT[((size_t)b * D + d) * HP2 + h0 + tx4] = v;
  }
}

// Main fused kernel (exact R14-verified structure): block = (32-frame tile,
// d-half, batch), 256 threads = 4 waves; wave w owns d in [dbase+64w, +64).
// Precomputed window (relative-index LDS staging), in-block premax over the
// window, exact per-chunk skip, double-buffered sA.
__launch_bounds__(256, 3)
__global__ void gup_kernel(const short* __restrict__ encT,
                           const f32x4* __restrict__ pk,
                           const int* __restrict__ win,
                           float* __restrict__ out,
                           int T, int TT) {
  constexpr int D  = 512;
  constexpr int AS = 72;           // sA row stride in halves (144B, 16B-aligned)

  __shared__ __align__(16) float sc[HP2], sq[HP2], sb[HP2];
  __shared__ float sden[32];
  __shared__ short sA[2][32 * AS];

  const int tid   = threadIdx.x;
  const int b     = blockIdx.y;
  const int tIdx  = blockIdx.x >> 1;
  const int t0    = tIdx * 32;
  const int dbase = (blockIdx.x & 1) * 256;

  const int cLo = win[(b * TT + tIdx) * 2 + 0];
  const int cHi = win[(b * TT + tIdx) * 2 + 1];
  const int base = cLo * 64;
  const int nC   = cHi - cLo;
  const int W64  = nC * 64;

  // phase 0: windowed packed params -> LDS (relative indexing)
  for (int i = tid; i < W64; i += 256) {
    const f32x4 v = pk[(size_t)b * HP2 + base + i];
    sc[i] = v[0]; sq[i] = v[1]; sb[i] = v[2];
  }
  __syncthreads();

  // premax: exact per-frame max over the window (8 lanes/frame, float4 reads)
  const int tfA = tid >> 3;               // frame 0..31
  const int hs8 = tid & 7;
  const float tA = (float)(t0 + tfA);
  float mA = -1e30f;
  for (int h4 = hs8 * 4; h4 < W64; h4 += 32) {
    const f32x4 cv = *(const f32x4*)&sc[h4];
    const f32x4 qv = *(const f32x4*)&sq[h4];
    const f32x4 bv = *(const f32x4*)&sb[h4];
#pragma unroll
    for (int j = 0; j < 4; ++j) {
      const float dd = tA - cv[j];
      mA = fmaxf(mA, fmaf(-dd * dd, qv[j], bv[j]));
    }
  }
  mA = fmaxf(mA, __shfl_xor(mA, 1));
  mA = fmaxf(mA, __shfl_xor(mA, 2));
  mA = fmaxf(mA, __shfl_xor(mA, 4));

  const int lane = tid & 63;
  const int wv   = tid >> 6;              // wave 0..3 -> d base dbase + 64*wv
  const int l15  = lane & 15;
  const int lq   = lane >> 4;

  f32x4 acc[2][4];
#pragma unroll
  for (int i = 0; i < 2; ++i)
#pragma unroll
    for (int j = 0; j < 4; ++j) acc[i][j] = (f32x4){0.f, 0.f, 0.f, 0.f};

  const int k8 = hs8 * 8;                 // this thread's 8 k-slots in sA
  float denAcc = 0.f;
  const short* bp = encT + ((size_t)b * D + dbase + wv * 64 + l15) * HP2 + base + lq * 8;

  int p = 0;
  for (int cc = 0; cc < nC; ++cc) {
    // A tile: unnormalized weights w = exp2(score - m), bf16 (RNE)
    const int hb = cc * 64 + k8;
    const f32x4 cv0 = *(const f32x4*)&sc[hb];
    const f32x4 qv0 = *(const f32x4*)&sq[hb];
    const f32x4 bv0 = *(const f32x4*)&sb[hb];
    const f32x4 cv1 = *(const f32x4*)&sc[hb + 4];
    const f32x4 qv1 = *(const f32x4*)&sq[hb + 4];
    const f32x4 bv1 = *(const f32x4*)&sb[hb + 4];
    short8 w;
    float denAdd = 0.f, pmax = 0.f;
#pragma unroll
    for (int j = 0; j < 4; ++j) {
      const float dd = tA - cv0[j];
      const float pv = __builtin_amdgcn_exp2f(fmaf(-dd * dd, qv0[j], bv0[j]) - mA);
      w[j] = bf16bits(pv);
      denAdd += bf16round(pv);
      pmax = fmaxf(pmax, pv);
    }
#pragma unroll
    for (int j = 0; j < 4; ++j) {
      const float dd = tA - cv1[j];
      const float pv = __builtin_amdgcn_exp2f(fmaf(-dd * dd, qv1[j], bv1[j]) - mA);
      w[4 + j] = bf16bits(pv);
      denAdd += bf16round(pv);
      pmax = fmaxf(pmax, pv);
    }

    // exact chunk skip: all weights < 2^-66 relative -> contributes nothing
    if (!__syncthreads_or(pmax > 1e-20f)) continue;

    denAcc += denAdd;
    *(short8*)&sA[p][tfA * AS + k8] = w;
    __syncthreads();

    // two 32-k sub-steps
#pragma unroll
    for (int kh = 0; kh < 2; ++kh) {
      short8 bfv[4];
#pragma unroll
      for (int nt = 0; nt < 4; ++nt)
        bfv[nt] = *(const short8*)(bp + (size_t)nt * 16 * HP2 + cc * 64 + kh * 32);
      short8 af[2];
#pragma unroll
      for (int mt = 0; mt < 2; ++mt)
        af[mt] = *(short8*)&sA[p][(mt * 16 + l15) * AS + kh * 32 + lq * 8];
      // swapped operands: acc holds C[d][t] -> lane gets 4 consecutive d
#pragma unroll
      for (int mt = 0; mt < 2; ++mt)
#pragma unroll
        for (int nt = 0; nt < 4; ++nt)
          acc[mt][nt] = __builtin_amdgcn_mfma_f32_16x16x32_bf16(bfv[nt], af[mt], acc[mt][nt], 0, 0, 0);
    }
    p ^= 1;   // double-buffered sA; or-barrier + barrier separate reuse
  }

  // denominators: reduce the 8 threads sharing a frame
  {
    float dsum = denAcc;
    dsum += __shfl_xor(dsum, 1);
    dsum += __shfl_xor(dsum, 2);
    dsum += __shfl_xor(dsum, 4);
    if (hs8 == 0) sden[tfA] = dsum;
  }
  __syncthreads();

  // epilogue: normalize and store float4 (4 consecutive d per thread)
#pragma unroll
  for (int mt = 0; mt < 2; ++mt) {
    const int tg = t0 + mt * 16 + l15;
    const float inv = 1.0f / sden[mt * 16 + l15];
    if (tg < T) {
#pragma unroll
      for (int nt = 0; nt < 4; ++nt) {
        f32x4 o;
#pragma unroll
        for (int i = 0; i < 4; ++i) o[i] = acc[mt][nt][i] * inv;
        *(f32x4*)&out[((size_t)b * T + tg) * D + dbase + wv * 64 + nt * 16 + lq * 4] = o;
      }
    }
  }
}

extern "C" void kernel_launch(void* const* d_in, const int* in_sizes, int n_in,
                              void* d_out, int out_size, void* d_ws, size_t ws_size,
                              hipStream_t stream) {
  const float* enc  = (const float*)d_in[0];
  const float* dur  = (const float*)d_in[1];
  const float* vars = (const float*)d_in[2];
  const int*   lens = (const int*)d_in[3];

  const int B = in_sizes[3];
  const int H = in_sizes[1] / B;
  const int D = in_sizes[0] / in_sizes[1];
  const int T = out_size / (B * D);
  const int TT = (T + 31) / 32;
  (void)n_in; (void)ws_size;

  f32x4* pk  = (f32x4*)d_ws;                       // B*HP2 float4
  int*   wn  = (int*)(pk + (size_t)B * HP2);       // B*TT*2
  short* encT = (short*)(wn + (size_t)B * TT * 2); // B*D*HP2 bf16 ~= 21 MB

  prepwin_kernel<<<B, 128, 0, stream>>>(dur, vars, lens, pk, wn, H, T, TT);

  dim3 tgrid(D / 64, HP2 / 64, B);
  transpose_kernel<<<tgrid, 256, 0, stream>>>(enc, encT, lens, H, D);

  dim3 grid(TT * 2, B);
  gup_kernel<<<grid, 256, 0, stream>>>(encT, pk, wn, (float*)d_out, T, TT);
}

// Round 17
// 67.652 us; speedup vs baseline: 1.1997x; 1.0673x over previous
//
#include <hip/hip_runtime.h>
#include <hip/hip_bf16.h>

using f32x4   = __attribute__((ext_vector_type(4))) float;
using short8  = __attribute__((ext_vector_type(8))) short;
using short4v = __attribute__((ext_vector_type(4))) short;

#define LOG2_2PI 2.6514961294723187f   // log2(2*pi)
#define L2E_HALF 0.7213475204444817f   // 0.5*log2(e)
#define HP2 640   // padded phoneme axis (10 x 64-chunks; 1280B encT rows)

__device__ __forceinline__ short bf16bits(float x) {
  unsigned u = __builtin_bit_cast(unsigned, x);
  u = (u + 0x7FFFu + ((u >> 16) & 1u)) >> 16;   // RNE; inputs are finite
  return (short)u;
}
__device__ __forceinline__ float bf16round(float x) {
  unsigned u = __builtin_bit_cast(unsigned, x);
  u = ((u + 0x7FFFu + ((u >> 16) & 1u)) >> 16) << 16;
  return __builtin_bit_cast(float, u);
}

// Fused producer: grid (D/64, HP2/64 + 1, B), 256 threads.
//  y < HP2/64          : transpose tile (enc f32 -> encT bf16, L-skip)
//  y == HP2/64, x == 0 : prep + win (prefix-scan -> pk, radius windows -> win)
// The two jobs are data-independent; fusing removes one launch serialization.
__global__ void producer_kernel(const float* __restrict__ enc,
                                const float* __restrict__ dur,
                                const float* __restrict__ vars,
                                const int* __restrict__ lens,
                                short* __restrict__ encT,
                                f32x4* __restrict__ pk, int* __restrict__ win,
                                int H, int D, int T, int TT) {
  __shared__ short sT[64][66];
  __shared__ float sc[HP2];
  __shared__ float sAux[8];

  const int b   = blockIdx.z;
  const int tid = threadIdx.x;
  const int L   = lens[b];

  if (blockIdx.y == HP2 / 64) {
    if (blockIdx.x != 0) return;
    // ---- prep + win body ----
    if (tid < 64) {
      const int l = tid;
      float run = 0.f, prevD = 0.f;
      float Gmax = 0.f, qMin = 1e30f, qMax = 0.f, bMin = 1e30f, bMax = -1e30f;
      for (int h0 = 0; h0 < HP2; h0 += 64) {
        const int h = h0 + l;
        const float d = (h < H) ? dur[(size_t)b * H + h] : 0.f;
        float x = d;
#pragma unroll
        for (int off = 1; off < 64; off <<= 1) {
          float y = __shfl_up(x, off);
          if (l >= off) x += y;
        }
        float dp = __shfl_up(d, 1);
        if (l == 0) dp = prevD;
        f32x4 e = (f32x4){0.f, 0.f, -1e30f, 0.f};
        if (h < H) {
          const float v = vars[(size_t)b * H + h];
          const float q = L2E_HALF / v;
          const float bc = -0.5f * (LOG2_2PI + __builtin_amdgcn_logf(v));
          e[0] = run + x - 0.5f * d;
          e[1] = q;
          e[2] = (h < L) ? bc : -1e30f;
          if (h < L) {
            qMin = fminf(qMin, q); qMax = fmaxf(qMax, q);
            bMin = fminf(bMin, bc); bMax = fmaxf(bMax, bc);
            if (h >= 1) Gmax = fmaxf(Gmax, 0.5f * (d + dp));  // center gap
          }
        }
        pk[(size_t)b * HP2 + h] = e;
        sc[h] = e[0];
        prevD = __shfl(d, 63);
        run += __shfl(x, 63);
      }
#pragma unroll
      for (int off = 1; off < 64; off <<= 1) {
        qMin = fminf(qMin, __shfl_xor(qMin, off));
        qMax = fmaxf(qMax, __shfl_xor(qMax, off));
        bMin = fminf(bMin, __shfl_xor(bMin, off));
        bMax = fmaxf(bMax, __shfl_xor(bMax, off));
        Gmax = fmaxf(Gmax, __shfl_xor(Gmax, off));
      }
      if (l == 0) {
        sAux[0] = Gmax; sAux[1] = qMin; sAux[2] = qMax; sAux[3] = bMin; sAux[4] = bMax;
      }
    }
    __syncthreads();

    const float Gmax = sAux[0], qMn = sAux[1], qMx = sAux[2];
    const float bMn  = sAux[3], bMx = sAux[4];
    const float c0 = sc[0], cL = sc[L - 1];
    for (int tile = tid; tile < TT; tile += 256) {
      const float tLo = (float)(tile * 32);
      const float tHi = (float)(min(tile * 32 + 31, T - 1));
      const float D0 = fmaxf(0.5f * Gmax, fmaxf(fmaxf(c0 - tLo, tHi - cL), 0.f));
      const float Wr = __fsqrt_rn(((bMx - bMn) + 65.f + qMx * D0 * D0) / qMn);
      int lo = 0, hi = L;
      const float thLo = tLo - Wr;
      while (lo < hi) { const int mid = (lo + hi) >> 1; if (sc[mid] < thLo) lo = mid + 1; else hi = mid; }
      int hLo = lo;
      int lo2 = hLo, hi2 = L;
      const float thHi = tHi + Wr;
      while (lo2 < hi2) { const int mid = (lo2 + hi2) >> 1; if (sc[mid] <= thHi) lo2 = mid + 1; else hi2 = mid; }
      int hHi = lo2;
      if (hHi <= hLo) { hLo = max(hLo - 1, 0); hHi = min(hLo + 2, L); }
      win[(b * TT + tile) * 2 + 0] = hLo >> 6;
      win[(b * TT + tile) * 2 + 1] = (hHi + 63) >> 6;
    }
    return;
  }

  // ---- transpose body (L-skip, verified R13) ----
  const int h0 = blockIdx.y * 64;
  const int d0 = blockIdx.x * 64;
  const int Lpad = (L + 63) & ~63;
  if (h0 >= Lpad) return;

  const int dc = (tid & 15) * 4;
  const int hr = tid >> 4;
#pragma unroll
  for (int ps = 0; ps < 4; ++ps) {
    const int hh = hr + ps * 16;
    const int h  = h0 + hh;
    f32x4 v = (h < H) ? *(const f32x4*)&enc[((size_t)b * H + h) * D + d0 + dc]
                      : (f32x4){0.f, 0.f, 0.f, 0.f};
#pragma unroll
    for (int j = 0; j < 4; ++j) sT[dc + j][hh] = bf16bits(v[j]);
  }
  __syncthreads();

  const int tx4 = (tid & 15) * 4;
  const int ty2 = tid >> 4;
#pragma unroll
  for (int i = 0; i < 4; ++i) {
    const int d = d0 + ty2 + i * 16;
    short4v v;
#pragma unroll
    for (int j = 0; j < 4; ++j) v[j] = sT[ty2 + i * 16][tx4 + j];
    *(short4v*)&encT[((size_t)b * D + d) * HP2 + h0 + tx4] = v;
  }
}

// Main fused kernel (R14/R16-verified structure + 1-barrier chunks +
// chunk-0 prefetch): block = (32-frame tile, d-half, batch), 256 threads.
__launch_bounds__(256, 3)
__global__ void gup_kernel(const short* __restrict__ encT,
                           const f32x4* __restrict__ pk,
                           const int* __restrict__ win,
                           float* __restrict__ out,
                           int T, int TT) {
  constexpr int D  = 512;
  constexpr int AS = 72;           // sA row stride in halves (144B, 16B-aligned)

  __shared__ __align__(16) float sc[HP2], sq[HP2], sb[HP2];
  __shared__ float sden[32];
  __shared__ short sA[2][32 * AS];

  const int tid   = threadIdx.x;
  const int b     = blockIdx.y;
  const int tIdx  = blockIdx.x >> 1;
  const int t0    = tIdx * 32;
  const int dbase = (blockIdx.x & 1) * 256;

  const int cLo = win[(b * TT + tIdx) * 2 + 0];
  const int cHi = win[(b * TT + tIdx) * 2 + 1];
  const int base = cLo * 64;
  const int nC   = cHi - cLo;
  const int W64  = nC * 64;

  const int lane = tid & 63;
  const int wv   = tid >> 6;              // wave 0..3 -> d base dbase + 64*wv
  const int l15  = lane & 15;
  const int lq   = lane >> 4;
  const short* bp = encT + ((size_t)b * D + dbase + wv * 64 + l15) * HP2 + base + lq * 8;

  // prefetch chunk 0, kh=0 B-fragments (independent of LDS staging)
  short8 pf[4];
#pragma unroll
  for (int nt = 0; nt < 4; ++nt)
    pf[nt] = *(const short8*)(bp + (size_t)nt * 16 * HP2);

  // phase 0: windowed packed params -> LDS (relative indexing)
  for (int i = tid; i < W64; i += 256) {
    const f32x4 v = pk[(size_t)b * HP2 + base + i];
    sc[i] = v[0]; sq[i] = v[1]; sb[i] = v[2];
  }
  __syncthreads();

  // premax: exact per-frame max over the window (8 lanes/frame, float4 reads)
  const int tfA = tid >> 3;               // frame 0..31
  const int hs8 = tid & 7;
  const float tA = (float)(t0 + tfA);
  float mA = -1e30f;
  for (int h4 = hs8 * 4; h4 < W64; h4 += 32) {
    const f32x4 cv = *(const f32x4*)&sc[h4];
    const f32x4 qv = *(const f32x4*)&sq[h4];
    const f32x4 bv = *(const f32x4*)&sb[h4];
#pragma unroll
    for (int j = 0; j < 4; ++j) {
      const float dd = tA - cv[j];
      mA = fmaxf(mA, fmaf(-dd * dd, qv[j], bv[j]));
    }
  }
  mA = fmaxf(mA, __shfl_xor(mA, 1));
  mA = fmaxf(mA, __shfl_xor(mA, 2));
  mA = fmaxf(mA, __shfl_xor(mA, 4));

  f32x4 acc[2][4];
#pragma unroll
  for (int i = 0; i < 2; ++i)
#pragma unroll
    for (int j = 0; j < 4; ++j) acc[i][j] = (f32x4){0.f, 0.f, 0.f, 0.f};

  const int k8 = hs8 * 8;                 // this thread's 8 k-slots in sA
  float denAcc = 0.f;

  int p = 0;
  for (int cc = 0; cc < nC; ++cc) {
    // A tile: unnormalized weights w = exp2(score - m), bf16 (RNE)
    const int hb = cc * 64 + k8;
    const f32x4 cv0 = *(const f32x4*)&sc[hb];
    const f32x4 qv0 = *(const f32x4*)&sq[hb];
    const f32x4 bv0 = *(const f32x4*)&sb[hb];
    const f32x4 cv1 = *(const f32x4*)&sc[hb + 4];
    const f32x4 qv1 = *(const f32x4*)&sq[hb + 4];
    const f32x4 bv1 = *(const f32x4*)&sb[hb + 4];
    short8 w;
    float denAdd = 0.f, pmax = 0.f;
#pragma unroll
    for (int j = 0; j < 4; ++j) {
      const float dd = tA - cv0[j];
      const float pv = __builtin_amdgcn_exp2f(fmaf(-dd * dd, qv0[j], bv0[j]) - mA);
      w[j] = bf16bits(pv);
      denAdd += bf16round(pv);
      pmax = fmaxf(pmax, pv);
    }
#pragma unroll
    for (int j = 0; j < 4; ++j) {
      const float dd = tA - cv1[j];
      const float pv = __builtin_amdgcn_exp2f(fmaf(-dd * dd, qv1[j], bv1[j]) - mA);
      w[4 + j] = bf16bits(pv);
      denAdd += bf16round(pv);
      pmax = fmaxf(pmax, pv);
    }

    // write tile BEFORE the or-barrier: the or-barrier both decides the skip
    // and orders sA visibility -> one barrier per chunk (double-buffered WAR
    // safety: laggard readers of buf q only overlap writers of q^1; rewrites
    // of q are separated by an intervening or-barrier).
    *(short8*)&sA[p][tfA * AS + k8] = w;

    // exact chunk skip: all weights < 2^-66 relative -> contributes nothing
    if (!__syncthreads_or(pmax > 1e-20f)) continue;

    denAcc += denAdd;

    // two 32-k sub-steps
#pragma unroll
    for (int kh = 0; kh < 2; ++kh) {
      short8 bfv[4];
      if (cc == 0 && kh == 0) {
#pragma unroll
        for (int nt = 0; nt < 4; ++nt) bfv[nt] = pf[nt];
      } else {
#pragma unroll
        for (int nt = 0; nt < 4; ++nt)
          bfv[nt] = *(const short8*)(bp + (size_t)nt * 16 * HP2 + cc * 64 + kh * 32);
      }
      short8 af[2];
#pragma unroll
      for (int mt = 0; mt < 2; ++mt)
        af[mt] = *(short8*)&sA[p][(mt * 16 + l15) * AS + kh * 32 + lq * 8];
      // swapped operands: acc holds C[d][t] -> lane gets 4 consecutive d
#pragma unroll
      for (int mt = 0; mt < 2; ++mt)
#pragma unroll
        for (int nt = 0; nt < 4; ++nt)
          acc[mt][nt] = __builtin_amdgcn_mfma_f32_16x16x32_bf16(bfv[nt], af[mt], acc[mt][nt], 0, 0, 0);
    }
    p ^= 1;   // flip only on live chunks
  }

  // denominators: reduce the 8 threads sharing a frame
  {
    float dsum = denAcc;
    dsum += __shfl_xor(dsum, 1);
    dsum += __shfl_xor(dsum, 2);
    dsum += __shfl_xor(dsum, 4);
    if (hs8 == 0) sden[tfA] = dsum;
  }
  __syncthreads();

  // epilogue: normalize and store float4 (4 consecutive d per thread)
#pragma unroll
  for (int mt = 0; mt < 2; ++mt) {
    const int tg = t0 + mt * 16 + l15;
    const float inv = 1.0f / sden[mt * 16 + l15];
    if (tg < T) {
#pragma unroll
      for (int nt = 0; nt < 4; ++nt) {
        f32x4 o;
#pragma unroll
        for (int i = 0; i < 4; ++i) o[i] = acc[mt][nt][i] * inv;
        *(f32x4*)&out[((size_t)b * T + tg) * D + dbase + wv * 64 + nt * 16 + lq * 4] = o;
      }
    }
  }
}

extern "C" void kernel_launch(void* const* d_in, const int* in_sizes, int n_in,
                              void* d_out, int out_size, void* d_ws, size_t ws_size,
                              hipStream_t stream) {
  const float* enc  = (const float*)d_in[0];
  const float* dur  = (const float*)d_in[1];
  const float* vars = (const float*)d_in[2];
  const int*   lens = (const int*)d_in[3];

  const int B = in_sizes[3];
  const int H = in_sizes[1] / B;
  const int D = in_sizes[0] / in_sizes[1];
  const int T = out_size / (B * D);
  const int TT = (T + 31) / 32;
  (void)n_in; (void)ws_size;

  f32x4* pk  = (f32x4*)d_ws;                       // B*HP2 float4
  int*   wn  = (int*)(pk + (size_t)B * HP2);       // B*TT*2
  short* encT = (short*)(wn + (size_t)B * TT * 2); // B*D*HP2 bf16 ~= 21 MB

  dim3 pgrid(D / 64, HP2 / 64 + 1, B);
  producer_kernel<<<pgrid, 256, 0, stream>>>(enc, dur, vars, lens, encT, pk, wn,
                                             H, D, T, TT);

  dim3 grid(TT * 2, B);
  gup_kernel<<<grid, 256, 0, stream>>>(encT, pk, wn, (float*)d_out, T, TT);
}

// Round 19
// 65.647 us; speedup vs baseline: 1.2364x; 1.0305x over previous
//
#include <hip/hip_runtime.h>
#include <hip/hip_bf16.h>

using f32x4   = __attribute__((ext_vector_type(4))) float;
using short8  = __attribute__((ext_vector_type(8))) short;
using short4v = __attribute__((ext_vector_type(4))) short;

#define LOG2_2PI 2.6514961294723187f   // log2(2*pi)
#define L2E_HALF 0.7213475204444817f   // 0.5*log2(e)
#define HP2 640   // padded phoneme axis (10 x 64-chunks; 1280B encT rows)

__device__ __forceinline__ short bf16bits(float x) {
  unsigned u = __builtin_bit_cast(unsigned, x);
  u = (u + 0x7FFFu + ((u >> 16) & 1u)) >> 16;   // RNE; inputs are finite
  return (short)u;
}
__device__ __forceinline__ float bf16round(float x) {
  unsigned u = __builtin_bit_cast(unsigned, x);
  u = ((u + 0x7FFFu + ((u >> 16) & 1u)) >> 16) << 16;
  return __builtin_bit_cast(float, u);
}

// Fused producer: grid (D/64, HP2/64 + 1, B), 256 threads.
//  y < HP2/64          : transpose tile (enc f32 -> encT bf16, L-skip)
//  y == HP2/64, x == 0 : prep + win (prefix-scan -> pk+aux, radius windows)
// pk centers are GLOBALLY MONOTONE (h >= H gets the final cumsum, d=0), so
// interval bounds from a chunk's first/last center are sound (R18 NaN fix).
__global__ void producer_kernel(const float* __restrict__ enc,
                                const float* __restrict__ dur,
                                const float* __restrict__ vars,
                                const int* __restrict__ lens,
                                short* __restrict__ encT,
                                f32x4* __restrict__ pk, int* __restrict__ win,
                                float* __restrict__ aux,
                                int H, int D, int T, int TT) {
  __shared__ short sT[64][66];
  __shared__ float sc[HP2];
  __shared__ float sAux[8];

  const int b   = blockIdx.z;
  const int tid = threadIdx.x;
  const int L   = lens[b];

  if (blockIdx.y == HP2 / 64) {
    if (blockIdx.x != 0) return;
    // ---- prep + win body ----
    if (tid < 64) {
      const int l = tid;
      float run = 0.f, prevD = 0.f;
      float Gmax = 0.f, qMin = 1e30f, qMax = 0.f, bMin = 1e30f, bMax = -1e30f;
      for (int h0 = 0; h0 < HP2; h0 += 64) {
        const int h = h0 + l;
        const float d = (h < H) ? dur[(size_t)b * H + h] : 0.f;
        float x = d;
#pragma unroll
        for (int off = 1; off < 64; off <<= 1) {
          float y = __shfl_up(x, off);
          if (l >= off) x += y;
        }
        float dp = __shfl_up(d, 1);
        if (l == 0) dp = prevD;
        // center computed UNCONDITIONALLY: for h >= H, d = 0 -> center is the
        // final cumsum (constant) -> globally monotone across [0, HP2).
        f32x4 e;
        e[0] = run + x - 0.5f * d;
        e[1] = 0.f;
        e[2] = -1e30f;
        e[3] = 0.f;
        if (h < H) {
          const float v = vars[(size_t)b * H + h];
          const float q = L2E_HALF / v;
          const float bc = -0.5f * (LOG2_2PI + __builtin_amdgcn_logf(v));
          e[1] = q;
          e[2] = (h < L) ? bc : -1e30f;
          if (h < L) {
            qMin = fminf(qMin, q); qMax = fmaxf(qMax, q);
            bMin = fminf(bMin, bc); bMax = fmaxf(bMax, bc);
            if (h >= 1) Gmax = fmaxf(Gmax, 0.5f * (d + dp));  // center gap
          }
        }
        pk[(size_t)b * HP2 + h] = e;
        sc[h] = e[0];
        prevD = __shfl(d, 63);
        run += __shfl(x, 63);
      }
#pragma unroll
      for (int off = 1; off < 64; off <<= 1) {
        qMin = fminf(qMin, __shfl_xor(qMin, off));
        qMax = fmaxf(qMax, __shfl_xor(qMax, off));
        bMin = fminf(bMin, __shfl_xor(bMin, off));
        bMax = fmaxf(bMax, __shfl_xor(bMax, off));
        Gmax = fmaxf(Gmax, __shfl_xor(Gmax, off));
      }
      if (l == 0) {
        sAux[0] = Gmax; sAux[1] = qMin; sAux[2] = qMax; sAux[3] = bMin; sAux[4] = bMax;
        float* ax = aux + b * 8;
        ax[0] = Gmax; ax[1] = qMin; ax[2] = qMax; ax[3] = bMin; ax[4] = bMax;
      }
    }
    __syncthreads();

    const float Gmax = sAux[0], qMn = sAux[1], qMx = sAux[2];
    const float bMn  = sAux[3], bMx = sAux[4];
    const float c0 = sc[0], cL = sc[L - 1];
    for (int tile = tid; tile < TT; tile += 256) {
      const float tLo = (float)(tile * 32);
      const float tHi = (float)(min(tile * 32 + 31, T - 1));
      const float D0 = fmaxf(0.5f * Gmax, fmaxf(fmaxf(c0 - tLo, tHi - cL), 0.f));
      const float Wr = __fsqrt_rn(((bMx - bMn) + 65.f + qMx * D0 * D0) / qMn);
      int lo = 0, hi = L;
      const float thLo = tLo - Wr;
      while (lo < hi) { const int mid = (lo + hi) >> 1; if (sc[mid] < thLo) lo = mid + 1; else hi = mid; }
      int hLo = lo;
      int lo2 = hLo, hi2 = L;
      const float thHi = tHi + Wr;
      while (lo2 < hi2) { const int mid = (lo2 + hi2) >> 1; if (sc[mid] <= thHi) lo2 = mid + 1; else hi2 = mid; }
      int hHi = lo2;
      if (hHi <= hLo) { hLo = max(hLo - 1, 0); hHi = min(hLo + 2, L); }
      win[(b * TT + tile) * 2 + 0] = hLo >> 6;
      win[(b * TT + tile) * 2 + 1] = (hHi + 63) >> 6;
    }
    return;
  }

  // ---- transpose body (L-skip, verified R13) ----
  const int h0 = blockIdx.y * 64;
  const int d0 = blockIdx.x * 64;
  const int Lpad = (L + 63) & ~63;
  if (h0 >= Lpad) return;

  const int dc = (tid & 15) * 4;
  const int hr = tid >> 4;
#pragma unroll
  for (int ps = 0; ps < 4; ++ps) {
    const int hh = hr + ps * 16;
    const int h  = h0 + hh;
    f32x4 v = (h < H) ? *(const f32x4*)&enc[((size_t)b * H + h) * D + d0 + dc]
                      : (f32x4){0.f, 0.f, 0.f, 0.f};
#pragma unroll
    for (int j = 0; j < 4; ++j) sT[dc + j][hh] = bf16bits(v[j]);
  }
  __syncthreads();

  const int tx4 = (tid & 15) * 4;
  const int ty2 = tid >> 4;
#pragma unroll
  for (int i = 0; i < 4; ++i) {
    const int d = d0 + ty2 + i * 16;
    short4v v;
#pragma unroll
    for (int j = 0; j < 4; ++j) v[j] = sT[ty2 + i * 16][tx4 + j];
    *(short4v*)&encT[((size_t)b * D + d) * HP2 + h0 + tx4] = v;
  }
}

// Main fused kernel (R17-verified structure + 4 blocks/CU + sound dead-chunk
// pretest): block = (32-frame tile, d-half, batch), 256 threads = 4 waves.
__launch_bounds__(256, 4)
__global__ void gup_kernel(const short* __restrict__ encT,
                           const f32x4* __restrict__ pk,
                           const int* __restrict__ win,
                           const float* __restrict__ aux,
                           float* __restrict__ out,
                           int T, int TT) {
  constexpr int D  = 512;
  constexpr int AS = 72;           // sA row stride in halves (144B, 16B-aligned)

  __shared__ __align__(16) float sc[HP2], sq[HP2], sb[HP2];
  __shared__ float sden[32];
  __shared__ short sA[2][32 * AS];

  const int tid   = threadIdx.x;
  const int b     = blockIdx.y;
  const int tIdx  = blockIdx.x >> 1;
  const int t0    = tIdx * 32;
  const int dbase = (blockIdx.x & 1) * 256;

  const int cLo = win[(b * TT + tIdx) * 2 + 0];
  const int cHi = win[(b * TT + tIdx) * 2 + 1];
  const int base = cLo * 64;
  const int nC   = cHi - cLo;
  const int W64  = nC * 64;

  const float qMn = aux[b * 8 + 1];
  const float bMx = aux[b * 8 + 4];

  const int lane = tid & 63;
  const int wv   = tid >> 6;              // wave 0..3 -> d base dbase + 64*wv
  const int l15  = lane & 15;
  const int lq   = lane >> 4;
  const short* bp = encT + ((size_t)b * D + dbase + wv * 64 + l15) * HP2 + base + lq * 8;

  // prefetch chunk 0, kh=0 B-fragments (independent of LDS staging)
  short8 pf[4];
#pragma unroll
  for (int nt = 0; nt < 4; ++nt)
    pf[nt] = *(const short8*)(bp + (size_t)nt * 16 * HP2);

  // phase 0: windowed packed params -> LDS (relative indexing)
  for (int i = tid; i < W64; i += 256) {
    const f32x4 v = pk[(size_t)b * HP2 + base + i];
    sc[i] = v[0]; sq[i] = v[1]; sb[i] = v[2];
  }
  __syncthreads();

  // premax: exact per-frame max over the window (8 lanes/frame, float4 reads)
  const int tfA = tid >> 3;               // frame 0..31
  const int hs8 = tid & 7;
  const float tA = (float)(t0 + tfA);
  float mA = -1e30f;
  for (int h4 = hs8 * 4; h4 < W64; h4 += 32) {
    const f32x4 cv = *(const f32x4*)&sc[h4];
    const f32x4 qv = *(const f32x4*)&sq[h4];
    const f32x4 bv = *(const f32x4*)&sb[h4];
#pragma unroll
    for (int j = 0; j < 4; ++j) {
      const float dd = tA - cv[j];
      mA = fmaxf(mA, fmaf(-dd * dd, qv[j], bv[j]));
    }
  }
  mA = fmaxf(mA, __shfl_xor(mA, 1));
  mA = fmaxf(mA, __shfl_xor(mA, 2));
  mA = fmaxf(mA, __shfl_xor(mA, 4));

  f32x4 acc[2][4];
#pragma unroll
  for (int i = 0; i < 2; ++i)
#pragma unroll
    for (int j = 0; j < 4; ++j) acc[i][j] = (f32x4){0.f, 0.f, 0.f, 0.f};

  const int k8 = hs8 * 8;                 // this thread's 8 k-slots in sA
  float denAcc = 0.f;

  int p = 0;
  for (int cc = 0; cc < nC; ++cc) {
    // per-frame dead-chunk pretest. Centers are globally monotone, so every
    // center in this chunk lies in [cfirst, clast]; best possible score
    // <= bMx - qMn*dmin^2. Below mA - 66 -> all weights < 2^-66 -> zeros.
    // The premax-argmax chunk always passes (ub >= mA) -> denominator >= 1.
    const float cfirst = sc[cc * 64];
    const float clast  = sc[cc * 64 + 63];
    const float dmin = fmaxf(fmaxf(cfirst - tA, tA - clast), 0.f);
    const bool frameLive = fmaf(-dmin * dmin, qMn, bMx) >= mA - 66.f;

    short8 w = (short8){0, 0, 0, 0, 0, 0, 0, 0};
    float denAdd = 0.f, pmax = 0.f;
    if (frameLive) {
      const int hb = cc * 64 + k8;
      const f32x4 cv0 = *(const f32x4*)&sc[hb];
      const f32x4 qv0 = *(const f32x4*)&sq[hb];
      const f32x4 bv0 = *(const f32x4*)&sb[hb];
      const f32x4 cv1 = *(const f32x4*)&sc[hb + 4];
      const f32x4 qv1 = *(const f32x4*)&sq[hb + 4];
      const f32x4 bv1 = *(const f32x4*)&sb[hb + 4];
#pragma unroll
      for (int j = 0; j < 4; ++j) {
        const float dd = tA - cv0[j];
        const float pv = __builtin_amdgcn_exp2f(fmaf(-dd * dd, qv0[j], bv0[j]) - mA);
        w[j] = bf16bits(pv);
        denAdd += bf16round(pv);
        pmax = fmaxf(pmax, pv);
      }
#pragma unroll
      for (int j = 0; j < 4; ++j) {
        const float dd = tA - cv1[j];
        const float pv = __builtin_amdgcn_exp2f(fmaf(-dd * dd, qv1[j], bv1[j]) - mA);
        w[4 + j] = bf16bits(pv);
        denAdd += bf16round(pv);
        pmax = fmaxf(pmax, pv);
      }
    }

    // write tile BEFORE the or-barrier (1 barrier/chunk; double-buffered WAR)
    *(short8*)&sA[p][tfA * AS + k8] = w;

    // exact chunk skip: all weights < 2^-66 relative -> contributes nothing
    if (!__syncthreads_or(pmax > 1e-20f)) continue;

    denAcc += denAdd;

    // two 32-k sub-steps
#pragma unroll
    for (int kh = 0; kh < 2; ++kh) {
      short8 bfv[4];
      if (cc == 0 && kh == 0) {
#pragma unroll
        for (int nt = 0; nt < 4; ++nt) bfv[nt] = pf[nt];
      } else {
#pragma unroll
        for (int nt = 0; nt < 4; ++nt)
          bfv[nt] = *(const short8*)(bp + (size_t)nt * 16 * HP2 + cc * 64 + kh * 32);
      }
      short8 af[2];
#pragma unroll
      for (int mt = 0; mt < 2; ++mt)
        af[mt] = *(short8*)&sA[p][(mt * 16 + l15) * AS + kh * 32 + lq * 8];
      // swapped operands: acc holds C[d][t] -> lane gets 4 consecutive d
#pragma unroll
      for (int mt = 0; mt < 2; ++mt)
#pragma unroll
        for (int nt = 0; nt < 4; ++nt)
          acc[mt][nt] = __builtin_amdgcn_mfma_f32_16x16x32_bf16(bfv[nt], af[mt], acc[mt][nt], 0, 0, 0);
    }
    p ^= 1;   // flip only on live chunks
  }

  // denominators: reduce the 8 threads sharing a frame
  {
    float dsum = denAcc;
    dsum += __shfl_xor(dsum, 1);
    dsum += __shfl_xor(dsum, 2);
    dsum += __shfl_xor(dsum, 4);
    if (hs8 == 0) sden[tfA] = dsum;
  }
  __syncthreads();

  // epilogue: normalize and store float4 (4 consecutive d per thread)
#pragma unroll
  for (int mt = 0; mt < 2; ++mt) {
    const int tg = t0 + mt * 16 + l15;
    const float inv = 1.0f / sden[mt * 16 + l15];
    if (tg < T) {
#pragma unroll
      for (int nt = 0; nt < 4; ++nt) {
        f32x4 o;
#pragma unroll
        for (int i = 0; i < 4; ++i) o[i] = acc[mt][nt][i] * inv;
        *(f32x4*)&out[((size_t)b * T + tg) * D + dbase + wv * 64 + nt * 16 + lq * 4] = o;
      }
    }
  }
}

extern "C" void kernel_launch(void* const* d_in, const int* in_sizes, int n_in,
                              void* d_out, int out_size, void* d_ws, size_t ws_size,
                              hipStream_t stream) {
  const float* enc  = (const float*)d_in[0];
  const float* dur  = (const float*)d_in[1];
  const float* vars = (const float*)d_in[2];
  const int*   lens = (const int*)d_in[3];

  const int B = in_sizes[3];
  const int H = in_sizes[1] / B;
  const int D = in_sizes[0] / in_sizes[1];
  const int T = out_size / (B * D);
  const int TT = (T + 31) / 32;
  (void)n_in; (void)ws_size;

  f32x4* pk  = (f32x4*)d_ws;                       // B*HP2 float4
  int*   wn  = (int*)(pk + (size_t)B * HP2);       // B*TT*2
  float* aux = (float*)(wn + (size_t)B * TT * 2);  // B*8
  short* encT = (short*)(aux + 8 * (size_t)B);     // B*D*HP2 bf16 ~= 21 MB

  dim3 pgrid(D / 64, HP2 / 64 + 1, B);
  producer_kernel<<<pgrid, 256, 0, stream>>>(enc, dur, vars, lens, encT, pk, wn,
                                             aux, H, D, T, TT);

  dim3 grid(TT * 2, B);
  gup_kernel<<<grid, 256, 0, stream>>>(encT, pk, wn, aux, (float*)d_out, T, TT);
}